// Round 1
// baseline (360.091 us; speedup 1.0000x reference)
//
#include <hip/hip_runtime.h>
#include <stdint.h>

#define M_DIM 512
#define K_DIM 8192
#define N_DIM 14336
#define NGRP  64      // K / 128 groups
#define GS    128     // group size (bytes per column in sB)
#define BN    64      // N columns per workgroup

typedef int   i32x4  __attribute__((ext_vector_type(4)));
typedef int   i32x16 __attribute__((ext_vector_type(16)));
typedef float f32x4  __attribute__((ext_vector_type(4)));

// ---------------- Kernel 1: per-row dynamic int8 quantization ----------------
// A: [M, K] fp32 -> qA int8 [M, K] row-major, s1[M] fp32 (= max|row|/127)
__global__ __launch_bounds__(256) void quant_rows(const float* __restrict__ A,
                                                  int8_t* __restrict__ qA,
                                                  float* __restrict__ s1)
{
    const int row = blockIdx.x;
    const int tid = threadIdx.x;
    const f32x4* src = (const f32x4*)(A + (size_t)row * K_DIM) + tid;

    f32x4 v[8];
#pragma unroll
    for (int i = 0; i < 8; ++i) v[i] = src[i * 256];

    float m = 0.0f;
#pragma unroll
    for (int i = 0; i < 8; ++i) {
        m = fmaxf(m, fmaxf(fmaxf(fabsf(v[i].x), fabsf(v[i].y)),
                           fmaxf(fabsf(v[i].z), fabsf(v[i].w))));
    }
#pragma unroll
    for (int off = 32; off > 0; off >>= 1)
        m = fmaxf(m, __shfl_xor(m, off));

    __shared__ float wmax[4];
    if ((tid & 63) == 0) wmax[tid >> 6] = m;
    __syncthreads();
    const float gm = fmaxf(fmaxf(wmax[0], wmax[1]), fmaxf(wmax[2], wmax[3]));
    const float s = gm / 127.0f;   // exact fp32 division, matches reference
    if (tid == 0) s1[row] = s;

    uint32_t* qrow = (uint32_t*)(qA + (size_t)row * K_DIM);
#pragma unroll
    for (int i = 0; i < 8; ++i) {
        uint32_t p = 0;
#pragma unroll
        for (int j = 0; j < 4; ++j) {
            float q = rintf(v[i][j] / s);             // round-half-even = np.round
            q = fminf(fmaxf(q, -128.0f), 127.0f);
            p |= ((uint32_t)(uint8_t)(int8_t)(int)q) << (8 * j);
        }
        qrow[tid + 256 * i] = p;
    }
}

// ---------------- Kernel 2: W4A8 group-quant GEMM ----------------
// Each WG: all 512 rows x 64 cols. 8 waves = 4 (M) x 2 (N); each wave owns
// 4 MFMA tiles of 32x32 (128 rows x 32 cols). B (w4) staged per group in LDS
// as int8, column-major [n][k] with XOR swizzle; A fragments read from L2.
__global__ __launch_bounds__(512, 2) void w4a8_gemm(
    const int8_t* __restrict__ qA, const float* __restrict__ s1,
    const int* __restrict__ w4, const float* __restrict__ sgrp,
    const float* __restrict__ schan, const float* __restrict__ bias,
    float* __restrict__ out)
{
    __shared__ int8_t sB[BN * GS];   // 8 KB

    const int tid  = threadIdx.x;
    const int lane = tid & 63;
    const int wid  = tid >> 6;
    const int mw   = wid >> 1;       // 0..3  (M wave)
    const int nw   = wid & 1;        // 0..1  (N wave)
    const int l31  = lane & 31;
    const int lhi  = lane >> 5;      // 0/1
    const int n0   = blockIdx.x * BN;
    const int colg = n0 + nw * 32 + l31;   // this lane's output column

    // staging mapping: thread handles a 4k x 4n int32 block of w4
    const int nq = tid & 15;         // 16 n-quads cover 64 columns
    const int kb = tid >> 4;         // 32 k-quads cover 128 k

    float facc[4][16];
#pragma unroll
    for (int i = 0; i < 4; ++i)
#pragma unroll
        for (int r = 0; r < 16; ++r) facc[i][r] = 0.0f;

    for (int g = 0; g < NGRP; ++g) {
        // ---- load w4 block (global, coalesced 16B per lane) ----
        const int  kbase = g * GS + kb * 4;
        const int* wp    = w4 + (size_t)kbase * N_DIM + n0 + nq * 4;
        i32x4 wv0 = *(const i32x4*)(wp);
        i32x4 wv1 = *(const i32x4*)(wp + N_DIM);
        i32x4 wv2 = *(const i32x4*)(wp + 2 * N_DIM);
        i32x4 wv3 = *(const i32x4*)(wp + 3 * N_DIM);

        __syncthreads();   // previous group's reads of sB are done
        // ---- pack -> int8 column-major [n][k], XOR-swizzled ----
#pragma unroll
        for (int j = 0; j < 4; ++j) {
            const int nl = nq * 4 + j;
            uint32_t p =  (uint32_t)(uint8_t)(int8_t)(wv0[j] - 8)
                       | ((uint32_t)(uint8_t)(int8_t)(wv1[j] - 8) << 8)
                       | ((uint32_t)(uint8_t)(int8_t)(wv2[j] - 8) << 16)
                       | ((uint32_t)(uint8_t)(int8_t)(wv3[j] - 8) << 24);
            *(uint32_t*)&sB[nl * GS + ((kb * 4) ^ ((nl & 7) << 4))] = p;
        }
        __syncthreads();

        const float sg = sgrp[(size_t)g * N_DIM + colg];  // per-lane group scale

        // B fragments for the 4 k-steps of this group
        i32x4 bfrag[4];
#pragma unroll
        for (int ks = 0; ks < 4; ++ks) {
            const int koff = ks * 32 + lhi * 16;
            bfrag[ks] = *(const i32x4*)&sB[(nw * 32 + l31) * GS
                                           + (koff ^ ((l31 & 7) << 4))];
        }

#pragma unroll
        for (int ms = 0; ms < 4; ++ms) {
            const int row = mw * 128 + ms * 32 + l31;
            const int8_t* ap = qA + (size_t)row * K_DIM + g * GS + lhi * 16;
            i32x16 iacc = {0,0,0,0,0,0,0,0,0,0,0,0,0,0,0,0};
#pragma unroll
            for (int ks = 0; ks < 4; ++ks) {
                i32x4 af = *(const i32x4*)(ap + ks * 32);
                iacc = __builtin_amdgcn_mfma_i32_32x32x32_i8(af, bfrag[ks], iacc, 0, 0, 0);
            }
            // fold per-group scale into fp32 accumulator (scale is per-column,
            // and col = lane&31 for all 16 C regs -> one scalar per lane)
#pragma unroll
            for (int r = 0; r < 16; ++r)
                facc[ms][r] += sg * (float)iacc[r];
        }
    }

    // ---- epilogue: D = facc * s1[m] * s_channel[n] + bias[n] ----
    const float sc = schan[colg];
    const float bv = bias[colg];
#pragma unroll
    for (int ms = 0; ms < 4; ++ms) {
        const int rbase = mw * 128 + ms * 32 + 4 * lhi;
#pragma unroll
        for (int r = 0; r < 16; ++r) {
            const int row = rbase + (r & 3) + 8 * (r >> 2);
            out[(size_t)row * N_DIM + colg] = facc[ms][r] * s1[row] * sc + bv;
        }
    }
}

extern "C" void kernel_launch(void* const* d_in, const int* in_sizes, int n_in,
                              void* d_out, int out_size, void* d_ws, size_t ws_size,
                              hipStream_t stream)
{
    const float* A     = (const float*)d_in[0];
    const int*   w4    = (const int*)  d_in[1];
    const float* sgrp  = (const float*)d_in[2];
    const float* schan = (const float*)d_in[3];
    const float* bias  = (const float*)d_in[4];
    float* out = (float*)d_out;

    // workspace layout: s1[512] at 0, qA (4 MB) at +4096
    float*  s1 = (float*)d_ws;
    int8_t* qA = (int8_t*)d_ws + 4096;

    quant_rows<<<dim3(M_DIM), dim3(256), 0, stream>>>(A, qA, s1);
    w4a8_gemm<<<dim3(N_DIM / BN), dim3(512), 0, stream>>>(qA, s1, w4, sgrp, schan, bias, out);
}

// Round 2
// 305.389 us; speedup vs baseline: 1.1791x; 1.1791x over previous
//
#include <hip/hip_runtime.h>
#include <stdint.h>

#define M_DIM 512
#define K_DIM 8192
#define N_DIM 14336
#define NGRP  64      // K / 128 groups
#define BN    64      // N columns per workgroup

typedef int   i32x4  __attribute__((ext_vector_type(4)));
typedef int   i32x16 __attribute__((ext_vector_type(16)));
typedef float f32x4  __attribute__((ext_vector_type(4)));

// ---------------- Kernel 1: per-row dynamic int8 quantization ----------------
// Writes qA in MFMA-fragment-native layout:
//   qA[((g*16 + tile)*4 + ks)*1024 + l31*32 + lhi*16 + b]
// where row = tile*32 + l31, k = g*128 + ks*32 + lhi*16 + b.
// A wave's A-fragment load in the GEMM is then one contiguous 2KB dwordx4.
__global__ __launch_bounds__(256) void quant_rows(const float* __restrict__ A,
                                                  uint8_t* __restrict__ qA,
                                                  float* __restrict__ s1)
{
    const int row  = blockIdx.x;
    const int tid  = threadIdx.x;
    const int tile = row >> 5;
    const int l31  = row & 31;
    const f32x4* src = (const f32x4*)(A + (size_t)row * K_DIM) + tid;

    f32x4 v[8];
#pragma unroll
    for (int i = 0; i < 8; ++i) v[i] = src[i * 256];

    float m = 0.0f;
#pragma unroll
    for (int i = 0; i < 8; ++i)
        m = fmaxf(m, fmaxf(fmaxf(fabsf(v[i].x), fabsf(v[i].y)),
                           fmaxf(fabsf(v[i].z), fabsf(v[i].w))));
#pragma unroll
    for (int off = 32; off > 0; off >>= 1)
        m = fmaxf(m, __shfl_xor(m, off));

    __shared__ float wmax[4];
    if ((tid & 63) == 0) wmax[tid >> 6] = m;
    __syncthreads();
    const float gm = fmaxf(fmaxf(wmax[0], wmax[1]), fmaxf(wmax[2], wmax[3]));
    const float s = gm / 127.0f;   // exact fp32 division, matches reference
    if (tid == 0) s1[row] = s;

#pragma unroll
    for (int i = 0; i < 8; ++i) {
        const int k0  = 4 * (tid + 256 * i);
        const int g   = k0 >> 7;
        const int ks  = (k0 >> 5) & 3;
        const int lhi = (k0 >> 4) & 1;
        const int b   = k0 & 15;
        uint32_t p = 0;
#pragma unroll
        for (int j = 0; j < 4; ++j) {
            float q = rintf(v[i][j] / s);             // round-half-even = np.round
            q = fminf(fmaxf(q, -128.0f), 127.0f);
            p |= ((uint32_t)(uint8_t)(int8_t)(int)q) << (8 * j);
        }
        *(uint32_t*)(qA + (size_t)(g * 16 + tile) * 4096 + ks * 1024
                        + l31 * 32 + lhi * 16 + b) = p;
    }
}

// ---------------- Kernel 2: W4A8 group-quant GEMM ----------------
// Block: 512 rows x 64 cols, 8 waves; wave w owns rows [w*64, w*64+64) x all
// 64 cols (2x2 tiles of 32x32). B double-buffered in LDS (int8, col-major,
// XOR-swizzled, one ds_write_b128 per thread per group). All global loads
// (w4 raw, A fragments, s_group) prefetched one group ahead; raw s_barrier
// (no vmcnt drain) keeps them in flight.

#define PACK_WRITE(BUF, WSRC) do {                                             \
    uint32_t u_[4];                                                            \
    _Pragma("unroll")                                                          \
    for (int j_ = 0; j_ < 4; ++j_) {                                           \
        u_[j_] =  (uint32_t)(uint8_t)(int8_t)(WSRC[4*j_+0] - 8)                \
               | ((uint32_t)(uint8_t)(int8_t)(WSRC[4*j_+1] - 8) << 8)          \
               | ((uint32_t)(uint8_t)(int8_t)(WSRC[4*j_+2] - 8) << 16)         \
               | ((uint32_t)(uint8_t)(int8_t)(WSRC[4*j_+3] - 8) << 24);        \
    }                                                                          \
    i32x4 wv_ = { (int)u_[0], (int)u_[1], (int)u_[2], (int)u_[3] };            \
    *(i32x4*)&sB[BUF][sc * 128 + ((sq * 16) ^ ((sc & 7) << 4))] = wv_;         \
} while (0)

#define BODY(G, RB, WB, ACUR, ANXT, SGC, SGN) do {                             \
    /* LDS -> B fragments for group G */                                       \
    i32x4 bf_[2][4];                                                           \
    _Pragma("unroll")                                                          \
    for (int nt = 0; nt < 2; ++nt)                                             \
    _Pragma("unroll")                                                          \
    for (int ks = 0; ks < 4; ++ks)                                             \
        bf_[nt][ks] = *(const i32x4*)&sB[RB][(nt*32 + l31) * 128               \
                        + ((ks*32 + lhi*16) ^ ((l31 & 7) << 4))];              \
    /* prefetch A fragments + group scales for G+1 */                          \
    {                                                                          \
        const int gn = ((G) + 1 < NGRP) ? (G) + 1 : NGRP - 1;                  \
        _Pragma("unroll")                                                      \
        for (int ms = 0; ms < 2; ++ms)                                         \
        _Pragma("unroll")                                                      \
        for (int ks = 0; ks < 4; ++ks)                                         \
            ANXT[ms][ks] = *(const i32x4*)(abase                               \
                + (size_t)((gn * 16 + 2 * w + ms) * 4 + ks) * 1024);           \
        SGN[0] = sgrp[(size_t)gn * N_DIM + n0 + l31];                          \
        SGN[1] = sgrp[(size_t)gn * N_DIM + n0 + 32 + l31];                     \
    }                                                                          \
    /* MFMA + per-group fp32 fold */                                           \
    _Pragma("unroll")                                                          \
    for (int nt = 0; nt < 2; ++nt)                                             \
    _Pragma("unroll")                                                          \
    for (int ms = 0; ms < 2; ++ms) {                                           \
        i32x16 ia = {0,0,0,0,0,0,0,0,0,0,0,0,0,0,0,0};                         \
        _Pragma("unroll")                                                      \
        for (int ks = 0; ks < 4; ++ks)                                         \
            ia = __builtin_amdgcn_mfma_i32_32x32x32_i8(ACUR[ms][ks],           \
                                                       bf_[nt][ks], ia, 0,0,0);\
        _Pragma("unroll")                                                      \
        for (int r = 0; r < 16; ++r)                                           \
            facc[ms][nt][r] += SGC[nt] * (float)ia[r];                         \
    }                                                                          \
    asm volatile("" ::: "memory");                                             \
    __builtin_amdgcn_s_barrier();   /* A: all waves done reading sB[RB] */     \
    /* stage B for G+1 into sB[WB] (wq holds raw w4 of G+1) */                 \
    PACK_WRITE(WB, wq);                                                        \
    /* issue raw w4 loads for G+2 */                                           \
    {                                                                          \
        const int gn2 = ((G) + 2 < NGRP) ? (G) + 2 : NGRP - 1;                 \
        _Pragma("unroll")                                                      \
        for (int i = 0; i < 16; ++i)                                           \
            wq[i] = w4[(size_t)(gn2 * 128 + sq * 16 + i) * N_DIM + n0 + sc];   \
    }                                                                          \
    asm volatile("s_waitcnt lgkmcnt(0)" ::: "memory");                         \
    __builtin_amdgcn_s_barrier();   /* B: sB[WB] visible to all */             \
} while (0)

__global__ __launch_bounds__(512, 2) void w4a8_gemm(
    const uint8_t* __restrict__ qA, const float* __restrict__ s1,
    const int* __restrict__ w4, const float* __restrict__ sgrp,
    const float* __restrict__ schan, const float* __restrict__ bias,
    float* __restrict__ out)
{
    __shared__ uint8_t sB[2][8192];   // 16 KB double buffer

    const int tid  = threadIdx.x;
    const int lane = tid & 63;
    const int w    = tid >> 6;        // wave 0..7 -> rows [w*64, w*64+64)
    const int l31  = lane & 31;
    const int lhi  = lane >> 5;
    const int n0   = blockIdx.x * BN;

    // staging mapping: one column, 16 consecutive k per thread
    const int sc = tid & 63;          // column 0..63
    const int sq = tid >> 6;          // 16-k chunk 0..7

    const uint8_t* abase = qA + l31 * 32 + lhi * 16;

    float facc[2][2][16];
#pragma unroll
    for (int a = 0; a < 2; ++a)
#pragma unroll
    for (int b = 0; b < 2; ++b)
#pragma unroll
    for (int r = 0; r < 16; ++r) facc[a][b][r] = 0.0f;

    // ---- prologue: raw(g0), A(g0), sg(g0), raw(g1); stage sB[0] ----
    int wq0[16], wq[16];
#pragma unroll
    for (int i = 0; i < 16; ++i)
        wq0[i] = w4[(size_t)(sq * 16 + i) * N_DIM + n0 + sc];

    i32x4 aA[2][4], aB[2][4];
    float sgA[2], sgB[2];
#pragma unroll
    for (int ms = 0; ms < 2; ++ms)
#pragma unroll
    for (int ks = 0; ks < 4; ++ks)
        aA[ms][ks] = *(const i32x4*)(abase + (size_t)((2 * w + ms) * 4 + ks) * 1024);
    sgA[0] = sgrp[n0 + l31];
    sgA[1] = sgrp[n0 + 32 + l31];

#pragma unroll
    for (int i = 0; i < 16; ++i)
        wq[i] = w4[(size_t)(128 + sq * 16 + i) * N_DIM + n0 + sc];

    PACK_WRITE(0, wq0);
    asm volatile("s_waitcnt lgkmcnt(0)" ::: "memory");
    __builtin_amdgcn_s_barrier();

    // ---- main loop: 64 groups, unrolled x2 for buffer/register ping-pong ----
#pragma unroll 1
    for (int g = 0; g < NGRP; g += 2) {
        BODY(g,     0, 1, aA, aB, sgA, sgB);
        BODY(g + 1, 1, 0, aB, aA, sgB, sgA);
    }

    // ---- epilogue: D = facc * s1[m] * s_channel[n] + bias[n] ----
#pragma unroll
    for (int nt = 0; nt < 2; ++nt) {
        const int col = n0 + nt * 32 + l31;
        const float sch = schan[col];
        const float bv  = bias[col];
#pragma unroll
        for (int ms = 0; ms < 2; ++ms) {
            const int rbase = w * 64 + ms * 32 + 4 * lhi;
#pragma unroll
            for (int r = 0; r < 16; ++r) {
                const int row = rbase + (r & 3) + 8 * (r >> 2);
                out[(size_t)row * N_DIM + col] = facc[ms][nt][r] * s1[row] * sch + bv;
            }
        }
    }
}

extern "C" void kernel_launch(void* const* d_in, const int* in_sizes, int n_in,
                              void* d_out, int out_size, void* d_ws, size_t ws_size,
                              hipStream_t stream)
{
    const float* A     = (const float*)d_in[0];
    const int*   w4    = (const int*)  d_in[1];
    const float* sgrp  = (const float*)d_in[2];
    const float* schan = (const float*)d_in[3];
    const float* bias  = (const float*)d_in[4];
    float* out = (float*)d_out;

    // workspace layout: s1[512] at 0, qA (4 MB, fragment-native) at +4096
    float*   s1 = (float*)d_ws;
    uint8_t* qA = (uint8_t*)d_ws + 4096;

    quant_rows<<<dim3(M_DIM), dim3(256), 0, stream>>>(A, qA, s1);
    w4a8_gemm<<<dim3(N_DIM / BN), dim3(512), 0, stream>>>(qA, s1, w4, sgrp, schan, bias, out);
}

// Round 3
// 183.740 us; speedup vs baseline: 1.9598x; 1.6621x over previous
//
#include <hip/hip_runtime.h>
#include <stdint.h>

#define M_DIM 512
#define K_DIM 8192
#define N_DIM 14336
#define NGRP  64      // K / 128 groups
#define BN    64      // N columns per workgroup

typedef int   i32x4  __attribute__((ext_vector_type(4)));
typedef int   i32x16 __attribute__((ext_vector_type(16)));
typedef float f32x4  __attribute__((ext_vector_type(4)));

// ---------------- Kernel 1: per-row dynamic int8 quantization ----------------
// Writes qA in MFMA-fragment-native layout:
//   qA[((g*16 + tile)*4 + ks)*1024 + l31*32 + lhi*16 + b]
// where row = tile*32 + l31, k = g*128 + ks*32 + lhi*16 + b.
__global__ __launch_bounds__(256) void quant_rows(const float* __restrict__ A,
                                                  uint8_t* __restrict__ qA,
                                                  float* __restrict__ s1)
{
    const int row  = blockIdx.x;
    const int tid  = threadIdx.x;
    const int tile = row >> 5;
    const int l31  = row & 31;
    const f32x4* src = (const f32x4*)(A + (size_t)row * K_DIM) + tid;

    f32x4 v[8];
#pragma unroll
    for (int i = 0; i < 8; ++i) v[i] = src[i * 256];

    float m = 0.0f;
#pragma unroll
    for (int i = 0; i < 8; ++i)
        m = fmaxf(m, fmaxf(fmaxf(fabsf(v[i].x), fabsf(v[i].y)),
                           fmaxf(fabsf(v[i].z), fabsf(v[i].w))));
#pragma unroll
    for (int off = 32; off > 0; off >>= 1)
        m = fmaxf(m, __shfl_xor(m, off));

    __shared__ float wmax[4];
    if ((tid & 63) == 0) wmax[tid >> 6] = m;
    __syncthreads();
    const float gm = fmaxf(fmaxf(wmax[0], wmax[1]), fmaxf(wmax[2], wmax[3]));
    const float s = gm / 127.0f;   // exact fp32 division, matches reference
    if (tid == 0) s1[row] = s;

#pragma unroll
    for (int i = 0; i < 8; ++i) {
        const int k0  = 4 * (tid + 256 * i);
        const int g   = k0 >> 7;
        const int ks  = (k0 >> 5) & 3;
        const int lhi = (k0 >> 4) & 1;
        const int b   = k0 & 15;
        uint32_t p = 0;
#pragma unroll
        for (int j = 0; j < 4; ++j) {
            float q = rintf(v[i][j] / s);             // round-half-even = np.round
            q = fminf(fmaxf(q, -128.0f), 127.0f);
            p |= ((uint32_t)(uint8_t)(int8_t)(int)q) << (8 * j);
        }
        *(uint32_t*)(qA + (size_t)(g * 16 + tile) * 4096 + ks * 1024
                        + l31 * 32 + lhi * 16 + b) = p;
    }
}

// ---------------- Kernel 2: W4A8 group-quant GEMM ----------------
// w4 is streamed HBM->LDS with global_load_lds DMA, triple-buffered (raw
// int32 [128k][64n] tiles). Each group: pack raw -> int8 col-major (XOR
// swizzled) in LDS, then MFMA. Counted vmcnt(12) before the barrier keeps
// DMA(G+2) + qA(G+1) in flight across barriers (T3/T4). s_group staged in
// LDS once so the loop's vmem stream is exactly {4 DMA + 8 qA} per group.

// DMA one group's w4 tile (32 KB int32) into raw[BUF]; lane i of wave w,
// instr j writes LDS bytes (j*512 + w*64 + lane)*16 (HW: uniform base+lane*16)
#define DMA_GROUP(BUF, G) do {                                                 \
    _Pragma("unroll")                                                          \
    for (int j_ = 0; j_ < 4; ++j_) {                                           \
        const int idx_ = j_ * 512 + tid;                                       \
        const int k_   = idx_ >> 4;                                            \
        const int c4_  = idx_ & 15;                                            \
        const int* gsrc_ = w4 + (size_t)((G) * 128 + k_) * N_DIM + n0 + c4_*4; \
        __builtin_amdgcn_global_load_lds(                                      \
            (const __attribute__((address_space(1))) void*)gsrc_,              \
            (__attribute__((address_space(3))) void*)&raw[BUF][(j_*512 + wv*64)*4], \
            16, 0, 0);                                                         \
    }                                                                          \
} while (0)

// pack raw[RBUF] (int32 [k][n]) -> pk[PBUF] (int8 col-major [n][k], swizzled)
#define PACK_GROUP(PBUF, RBUF) do {                                            \
    i32x4 r_[4];                                                               \
    _Pragma("unroll")                                                          \
    for (int j_ = 0; j_ < 4; ++j_)                                             \
        r_[j_] = *(const i32x4*)&raw[RBUF][(kq * 4 + j_) * 64 + c4 * 4];       \
    _Pragma("unroll")                                                          \
    for (int c_ = 0; c_ < 4; ++c_) {                                           \
        const int col_ = c4 * 4 + c_;                                          \
        uint32_t d_ =  ((uint32_t)(r_[0][c_] - 8) & 0xFFu)                     \
                    | (((uint32_t)(r_[1][c_] - 8) & 0xFFu) << 8)               \
                    | (((uint32_t)(r_[2][c_] - 8) & 0xFFu) << 16)              \
                    | (((uint32_t)(r_[3][c_] - 8) & 0xFFu) << 24);             \
        *(uint32_t*)&pk[PBUF][col_ * 128 + ((kq * 4) ^ ((col_ & 7) << 4))] = d_; \
    }                                                                          \
} while (0)

#define BODY(G, RP, WP, ACUR, ANXT) do {                                       \
    /* 1: issue DMA for G+2 */                                                 \
    { const int gd_ = ((G) + 2 < NGRP) ? (G) + 2 : NGRP - 1;                   \
      DMA_GROUP(((G) + 2) % 3, gd_); }                                         \
    /* 2: B fragments + group scales from LDS */                               \
    i32x4 bf_[2][4];                                                           \
    _Pragma("unroll")                                                          \
    for (int nt = 0; nt < 2; ++nt)                                             \
    _Pragma("unroll")                                                          \
    for (int ks = 0; ks < 4; ++ks)                                             \
        bf_[nt][ks] = *(const i32x4*)&pk[RP][(nt*32 + l31) * 128               \
                        + ((ks*32 + lhi*16) ^ ((l31 & 7) << 4))];              \
    const float sg0_ = sgl[(G) * 64 + l31];                                    \
    const float sg1_ = sgl[(G) * 64 + 32 + l31];                               \
    /* 3: prefetch A fragments for G+1 */                                      \
    { const int gn_ = ((G) + 1 < NGRP) ? (G) + 1 : NGRP - 1;                   \
      _Pragma("unroll")                                                        \
      for (int ms = 0; ms < 2; ++ms)                                           \
      _Pragma("unroll")                                                        \
      for (int ks = 0; ks < 4; ++ks)                                           \
          ANXT[ms][ks] = *(const i32x4*)(abase                                 \
              + (size_t)((gn_ * 16 + 2 * wv + ms) * 4 + ks) * 1024); }         \
    /* 4: MFMA + per-group fp32 fold */                                        \
    _Pragma("unroll")                                                          \
    for (int nt = 0; nt < 2; ++nt) {                                           \
        const float sgv_ = nt ? sg1_ : sg0_;                                   \
        _Pragma("unroll")                                                      \
        for (int ms = 0; ms < 2; ++ms) {                                       \
            i32x16 ia = {0,0,0,0,0,0,0,0,0,0,0,0,0,0,0,0};                     \
            _Pragma("unroll")                                                  \
            for (int ks = 0; ks < 4; ++ks)                                     \
                ia = __builtin_amdgcn_mfma_i32_32x32x32_i8(ACUR[ms][ks],       \
                                                    bf_[nt][ks], ia, 0, 0, 0); \
            _Pragma("unroll")                                                  \
            for (int r = 0; r < 16; ++r)                                       \
                facc[ms][nt][r] += sgv_ * (float)ia[r];                        \
        }                                                                      \
    }                                                                          \
    /* 5: counted drain (DMA(G+1) done; DMA(G+2)+qA(G+1) stay in flight) */    \
    __builtin_amdgcn_sched_barrier(0);                                         \
    asm volatile("s_waitcnt vmcnt(12)" ::: "memory");                          \
    __builtin_amdgcn_sched_barrier(0);                                         \
    __builtin_amdgcn_s_barrier();                                              \
    __builtin_amdgcn_sched_barrier(0);                                         \
    /* 6: pack group G+1 */                                                    \
    PACK_GROUP(WP, ((G) + 1) % 3);                                             \
    /* 7: pack visible to all */                                               \
    asm volatile("s_waitcnt lgkmcnt(0)" ::: "memory");                         \
    __builtin_amdgcn_s_barrier();                                              \
    __builtin_amdgcn_sched_barrier(0);                                         \
} while (0)

__global__ __launch_bounds__(512) void w4a8_gemm(
    const uint8_t* __restrict__ qA, const float* __restrict__ s1,
    const int* __restrict__ w4, const float* __restrict__ sgrp,
    const float* __restrict__ schan, const float* __restrict__ bias,
    float* __restrict__ out)
{
    __shared__ int     raw[3][128 * 64];   // 3 x 32 KB raw int32 w4 tiles
    __shared__ uint8_t pk[2][64 * 128];    // 2 x 8 KB packed int8 (col-major)
    __shared__ float   sgl[NGRP * BN];     // 16 KB staged group scales

    const int tid  = threadIdx.x;
    const int lane = tid & 63;
    const int wv   = tid >> 6;        // wave 0..7 -> rows [wv*64, wv*64+64)
    const int l31  = lane & 31;
    const int lhi  = lane >> 5;
    const int n0   = blockIdx.x * BN;
    const int c4   = tid & 15;        // pack: column quad
    const int kq   = tid >> 4;        // pack: k quad (0..31)

    const uint8_t* abase = qA + l31 * 32 + lhi * 16;

    float facc[2][2][16];
#pragma unroll
    for (int a = 0; a < 2; ++a)
#pragma unroll
    for (int b = 0; b < 2; ++b)
#pragma unroll
    for (int r = 0; r < 16; ++r) facc[a][b][r] = 0.0f;

    // ---- prologue ----
    // stage s_group for our 64 columns (8 global loads -> LDS)
#pragma unroll
    for (int j = 0; j < 8; ++j) {
        const int idx = tid + j * 512;              // idx = g*64 + c
        sgl[idx] = sgrp[(size_t)(idx >> 6) * N_DIM + n0 + (idx & 63)];
    }
    DMA_GROUP(0, 0);
    DMA_GROUP(1, 1);

    i32x4 aA[2][4], aB[2][4];
#pragma unroll
    for (int ms = 0; ms < 2; ++ms)
#pragma unroll
    for (int ks = 0; ks < 4; ++ks)
        aA[ms][ks] = *(const i32x4*)(abase + (size_t)((2 * wv + ms) * 4 + ks) * 1024);

    __builtin_amdgcn_sched_barrier(0);
    asm volatile("s_waitcnt vmcnt(12)" ::: "memory");   // DMA(0)+sg done
    __builtin_amdgcn_sched_barrier(0);
    __builtin_amdgcn_s_barrier();
    __builtin_amdgcn_sched_barrier(0);
    PACK_GROUP(0, 0);
    asm volatile("s_waitcnt lgkmcnt(0)" ::: "memory");
    __builtin_amdgcn_s_barrier();
    __builtin_amdgcn_sched_barrier(0);

    // ---- main loop: ping-pong pk buffers and A-fragment registers ----
#pragma unroll 1
    for (int g = 0; g < NGRP; g += 2) {
        BODY(g,     0, 1, aA, aB);
        BODY(g + 1, 1, 0, aB, aA);
    }

    // ---- epilogue: D = facc * s1[m] * s_channel[n] + bias[n] ----
#pragma unroll
    for (int nt = 0; nt < 2; ++nt) {
        const int col = n0 + nt * 32 + l31;
        const float sch = schan[col];
        const float bv  = bias[col];
#pragma unroll
        for (int ms = 0; ms < 2; ++ms) {
            const int rbase = wv * 64 + ms * 32 + 4 * lhi;
#pragma unroll
            for (int r = 0; r < 16; ++r) {
                const int row = rbase + (r & 3) + 8 * (r >> 2);
                out[(size_t)row * N_DIM + col] = facc[ms][nt][r] * s1[row] * sch + bv;
            }
        }
    }
}

extern "C" void kernel_launch(void* const* d_in, const int* in_sizes, int n_in,
                              void* d_out, int out_size, void* d_ws, size_t ws_size,
                              hipStream_t stream)
{
    const float* A     = (const float*)d_in[0];
    const int*   w4    = (const int*)  d_in[1];
    const float* sgrp  = (const float*)d_in[2];
    const float* schan = (const float*)d_in[3];
    const float* bias  = (const float*)d_in[4];
    float* out = (float*)d_out;

    // workspace layout: s1[512] at 0, qA (4 MB, fragment-native) at +4096
    float*   s1 = (float*)d_ws;
    uint8_t* qA = (uint8_t*)d_ws + 4096;

    quant_rows<<<dim3(M_DIM), dim3(256), 0, stream>>>(A, qA, s1);
    w4a8_gemm<<<dim3(N_DIM / BN), dim3(512), 0, stream>>>(qA, s1, w4, sgrp, schan, bias, out);
}